// Round 1
// baseline (500.076 us; speedup 1.0000x reference)
//
#include <hip/hip_runtime.h>
#include <math.h>

#pragma clang fp contract(off)

#define BN 4
#define SX 512
#define SY 512
#define NPIX (BN * SX * SY)
#define MU 5

struct DogW  { float g[7];  float tw; };
struct FdogW { float g[10]; float tw; };

__device__ __forceinline__ float img_at(const float* __restrict__ img, int b, int x, int y) {
    if (x < 0 || x >= SX || y < 0 || y >= SY) return 0.0f;
    return img[(size_t)b * SX * SY + (size_t)x * SY + y];
}

// Stage 1: Sobel -> mag (unnormalized), initial tangent field, global max(mag)
__global__ void k_sobel(const float* __restrict__ img, float* __restrict__ mag,
                        float2* __restrict__ tang, unsigned int* __restrict__ maxbits) {
#pragma clang fp contract(off)
    int yi = blockIdx.x * blockDim.x + threadIdx.x;
    int xi = blockIdx.y;
    int b  = blockIdx.z;

    float v00 = img_at(img, b, xi - 1, yi - 1);
    float v01 = img_at(img, b, xi - 1, yi    );
    float v02 = img_at(img, b, xi - 1, yi + 1);
    float v10 = img_at(img, b, xi,     yi - 1);
    float v12 = img_at(img, b, xi,     yi + 1);
    float v20 = img_at(img, b, xi + 1, yi - 1);
    float v21 = img_at(img, b, xi + 1, yi    );
    float v22 = img_at(img, b, xi + 1, yi + 1);

    // k = [[-1,-2,-1],[0,0,0],[1,2,1]] cross-correlation, row-major tap order
    float s0 = (-1.0f * v00);
    s0 = s0 + (-2.0f * v01);
    s0 = s0 + (-1.0f * v02);
    s0 = s0 + ( 1.0f * v20);
    s0 = s0 + ( 2.0f * v21);
    s0 = s0 + ( 1.0f * v22);
    // k.T = [[-1,0,1],[-2,0,2],[-1,0,1]]
    float s1 = (-1.0f * v00);
    s1 = s1 + ( 1.0f * v02);
    s1 = s1 + (-2.0f * v10);
    s1 = s1 + ( 2.0f * v12);
    s1 = s1 + (-1.0f * v20);
    s1 = s1 + ( 1.0f * v22);

    float m = sqrtf((s0 * s0) + (s1 * s1));
    size_t idx = (size_t)b * SX * SY + (size_t)xi * SY + yi;
    mag[idx] = m;

    float tx = -s1, ty = s0;
    float n = sqrtf((tx * tx) + (ty * ty));
    float d = (n == 0.0f) ? 1.0f : n;
    tang[idx] = make_float2(tx / d, ty / d);

    __shared__ float red[256];
    red[threadIdx.x] = m;
    __syncthreads();
    for (int s = 128; s > 0; s >>= 1) {
        if ((int)threadIdx.x < s) red[threadIdx.x] = fmaxf(red[threadIdx.x], red[threadIdx.x + s]);
        __syncthreads();
    }
    if (threadIdx.x == 0) atomicMax(maxbits, __float_as_uint(red[0]));
}

// Stage 2: mag /= max(mag)
__global__ void k_norm(float* __restrict__ mag, const unsigned int* __restrict__ maxbits) {
    int i = blockIdx.x * blockDim.x + threadIdx.x;
    float mx = __uint_as_float(*maxbits);
    mag[i] = mag[i] / mx;
}

// Stage 3: one ETF smoothing pass (vert=1: vary x; vert=0: vary y)
__global__ void k_etf(const float2* __restrict__ tsrc, float2* __restrict__ tdst,
                      const float* __restrict__ mag, int vert) {
#pragma clang fp contract(off)
    int yi = blockIdx.x * blockDim.x + threadIdx.x;
    int xi = blockIdx.y;
    int b  = blockIdx.z;
    size_t base = (size_t)b * SX * SY;
    size_t idx  = base + (size_t)xi * SY + yi;

    float  cm = mag[idx];
    float2 ct = tsrc[idx];

    float sx = 0.0f, sy = 0.0f;
    for (int k = -MU; k <= MU; ++k) {
        int nx = xi + (vert ? k : 0);
        int ny = yi + (vert ? 0 : k);
        if (nx < 0 || nx >= SX || ny < 0 || ny >= SY) continue;  // padded zeros give w*ty == 0
        size_t nidx = base + (size_t)nx * SY + ny;
        float  nm = mag[nidx];
        float2 nt = tsrc[nidx];
        float dot = (ct.x * nt.x) + (ct.y * nt.y);
        float th  = (float)tanh((double)(nm - cm));     // ETA == 1.0 multiply is exact
        float w   = ((th + 1.0f) * dot) * 0.5f;
        sx = sx + (nt.x * w);
        sy = sy + (nt.y * w);
    }
    float n = sqrtf((sx * sx) + (sy * sy));
    float d = (n == 0.0f) ? 1.0f : n;
    tdst[idx] = make_float2(sx / d, sy / d);
}

// Stage 4: DoG along the perpendicular of the ETF
__global__ void k_dog(const float* __restrict__ img, const float2* __restrict__ etf,
                      float* __restrict__ dog, DogW w) {
#pragma clang fp contract(off)
    int yi = blockIdx.x * blockDim.x + threadIdx.x;
    int xi = blockIdx.y;
    int b  = blockIdx.z;
    size_t base = (size_t)b * SX * SY;
    size_t idx  = base + (size_t)xi * SY + yi;

    float2 e = etf[idx];
    float perx = -e.y;
    float pery =  e.x;
    float xf = (float)xi, yf = (float)yi;

    float acc = 0.0f;
    for (int t = -3; t <= 3; ++t) {
        float tf  = (float)t;
        float ptx = xf + (perx * tf);
        float pty = yf + (pery * tf);
        int px = (int)rintf(fminf(fmaxf(ptx, 0.0f), (float)(SX - 1)));
        int py = (int)rintf(fminf(fmaxf(pty, 0.0f), (float)(SY - 1)));
        float il = img[base + (size_t)px * SY + py];
        acc = acc + (il * w.g[t + 3]);
    }
    dog[idx] = acc / w.tw;
}

// Stage 5: FDoG trace along the flow + tanh threshold -> int32 edges
__global__ void k_fdog(const float* __restrict__ dog, const float2* __restrict__ etf,
                       int* __restrict__ out, FdogW w) {
#pragma clang fp contract(off)
    int yi = blockIdx.x * blockDim.x + threadIdx.x;
    int xi = blockIdx.y;
    int b  = blockIdx.z;
    size_t base = (size_t)b * SX * SY;
    size_t idx  = base + (size_t)xi * SY + yi;

    float acc = 0.0f;

    // s_dir = -1, s = 1..9 (step first, then sample)
    int px = xi, py = yi;
    for (int s = 1; s <= 9; ++s) {
        float2 e = etf[base + (size_t)px * SY + py];
        float fx = (float)px + (e.x * -1.0f);
        float fy = (float)py + (e.y * -1.0f);
        px = (int)rintf(fminf(fmaxf(fx, 0.0f), (float)(SX - 1)));
        py = (int)rintf(fminf(fmaxf(fy, 0.0f), (float)(SY - 1)));
        acc = acc + (dog[base + (size_t)px * SY + py] * w.g[s]);
    }

    // s_dir = +1, s = 0 (no step), then s = 1..9
    px = xi; py = yi;
    acc = acc + (dog[base + (size_t)px * SY + py] * w.g[0]);
    for (int s = 1; s <= 9; ++s) {
        float2 e = etf[base + (size_t)px * SY + py];
        float fx = (float)px + (e.x * 1.0f);
        float fy = (float)py + (e.y * 1.0f);
        px = (int)rintf(fminf(fmaxf(fx, 0.0f), (float)(SX - 1)));
        py = (int)rintf(fminf(fmaxf(fy, 0.0f), (float)(SY - 1)));
        acc = acc + (dog[base + (size_t)px * SY + py] * w.g[s]);
    }

    float fv = acc / w.tw;
    float th = 1.0f + (float)tanh((double)fv);
    out[idx] = ((fv < 0.0f) && (th < 0.7f)) ? 0 : 1;
}

static double gpdf(double v, double sig) {
    return exp(-(v * v) / (2.0 * sig * sig)) / (sqrt(2.0 * M_PI) * sig);
}

extern "C" void kernel_launch(void* const* d_in, const int* in_sizes, int n_in,
                              void* d_out, int out_size, void* d_ws, size_t ws_size,
                              hipStream_t stream) {
    const float* img = (const float*)d_in[0];
    int* out = (int*)d_out;
    char* ws = (char*)d_ws;

    // Workspace layout (20 MB + 4 B):
    //   mag:  [0, 4MB)          fp32 NPIX
    //   tA:   [4MB, 12MB)       float2 NPIX
    //   tB:   [12MB, 20MB)      float2 NPIX  (dog aliases first 4MB after ETF passes)
    //   maxbits: [20MB, 20MB+4)
    float*        mag     = (float*)(ws);
    float2*       tA      = (float2*)(ws + (size_t)4  * 1024 * 1024);
    float2*       tB      = (float2*)(ws + (size_t)12 * 1024 * 1024);
    float*        dog     = (float*)(ws + (size_t)12 * 1024 * 1024);  // reuses tB after ETF done
    unsigned int* maxbits = (unsigned int*)(ws + (size_t)20 * 1024 * 1024);

    hipMemsetAsync(maxbits, 0, sizeof(unsigned int), stream);

    dim3 blk(256, 1, 1);
    dim3 grd(SY / 256, SX, BN);

    k_sobel<<<grd, blk, 0, stream>>>(img, mag, tA, maxbits);
    k_norm<<<NPIX / 256, 256, 0, stream>>>(mag, maxbits);

    // 3 iterations x (V then H); final result lands back in tA
    float2* src = tA;
    float2* dst = tB;
    for (int it = 0; it < 3; ++it) {
        k_etf<<<grd, blk, 0, stream>>>(src, dst, mag, 1);  // V
        { float2* t = src; src = dst; dst = t; }
        k_etf<<<grd, blk, 0, stream>>>(src, dst, mag, 0);  // H
        { float2* t = src; src = dst; dst = t; }
    }
    // src == tA holds the final ETF; tB is now free -> dog aliases it.

    DogW dw;
    {
        double tw = 0.0;
        for (int t = -3; t <= 3; ++t) {
            double g = gpdf((double)t, 1.0) - 0.99 * gpdf((double)t, 1.6);
            dw.g[t + 3] = (float)g;
            tw += g;
        }
        dw.tw = (float)tw;
    }
    k_dog<<<grd, blk, 0, stream>>>(img, src, dog, dw);

    FdogW fw;
    {
        for (int s = 0; s <= 9; ++s) fw.g[s] = (float)gpdf((double)s, 3.0);
        double tw = 0.0;
        for (int s = 1; s <= 9; ++s) tw += gpdf((double)s, 3.0);  // dir = -1
        for (int s = 0; s <= 9; ++s) tw += gpdf((double)s, 3.0);  // dir = +1
        fw.tw = (float)tw;
    }
    k_fdog<<<grd, blk, 0, stream>>>(dog, src, out, fw);
}

// Round 2
// 285.720 us; speedup vs baseline: 1.7502x; 1.7502x over previous
//
#include <hip/hip_runtime.h>
#include <math.h>

#pragma clang fp contract(off)

#define BN 4
#define SX 512
#define SY 512
#define NPIX (BN * SX * SY)
#define MU 5
#define MB (1024 * 1024)

struct DogW  { float g[7];  float tw; };
struct FdogW { float g[10]; float tw; };

__device__ __forceinline__ float img_at(const float* __restrict__ img, int b, int x, int y) {
    if (x < 0 || x >= SX || y < 0 || y >= SY) return 0.0f;
    return img[(size_t)b * SX * SY + (size_t)x * SY + y];
}

// Stage 1: Sobel -> mag (unnormalized), initial tangent field, global max(mag)
__global__ void k_sobel(const float* __restrict__ img, float* __restrict__ mag,
                        float2* __restrict__ tang, unsigned int* __restrict__ maxbits) {
#pragma clang fp contract(off)
    int yi = blockIdx.x * blockDim.x + threadIdx.x;
    int xi = blockIdx.y;
    int b  = blockIdx.z;

    float v00 = img_at(img, b, xi - 1, yi - 1);
    float v01 = img_at(img, b, xi - 1, yi    );
    float v02 = img_at(img, b, xi - 1, yi + 1);
    float v10 = img_at(img, b, xi,     yi - 1);
    float v12 = img_at(img, b, xi,     yi + 1);
    float v20 = img_at(img, b, xi + 1, yi - 1);
    float v21 = img_at(img, b, xi + 1, yi    );
    float v22 = img_at(img, b, xi + 1, yi + 1);

    float s0 = (-1.0f * v00);
    s0 = s0 + (-2.0f * v01);
    s0 = s0 + (-1.0f * v02);
    s0 = s0 + ( 1.0f * v20);
    s0 = s0 + ( 2.0f * v21);
    s0 = s0 + ( 1.0f * v22);
    float s1 = (-1.0f * v00);
    s1 = s1 + ( 1.0f * v02);
    s1 = s1 + (-2.0f * v10);
    s1 = s1 + ( 2.0f * v12);
    s1 = s1 + (-1.0f * v20);
    s1 = s1 + ( 1.0f * v22);

    float m = sqrtf((s0 * s0) + (s1 * s1));
    size_t idx = (size_t)b * SX * SY + (size_t)xi * SY + yi;
    mag[idx] = m;

    float tx = -s1, ty = s0;
    float n = sqrtf((tx * tx) + (ty * ty));
    float d = (n == 0.0f) ? 1.0f : n;
    tang[idx] = make_float2(tx / d, ty / d);

    __shared__ float red[256];
    red[threadIdx.x] = m;
    __syncthreads();
    for (int s = 128; s > 0; s >>= 1) {
        if ((int)threadIdx.x < s) red[threadIdx.x] = fmaxf(red[threadIdx.x], red[threadIdx.x + s]);
        __syncthreads();
    }
    if (threadIdx.x == 0) atomicMax(maxbits, __float_as_uint(red[0]));
}

// Stage 2: mag /= max(mag)
__global__ void k_norm(float* __restrict__ mag, const unsigned int* __restrict__ maxbits) {
    int i = blockIdx.x * blockDim.x + threadIdx.x;
    float mx = __uint_as_float(*maxbits);
    mag[i] = mag[i] / mx;
}

// Precompute tanh difference fields once (mag is constant across all ETF iters).
// TV[k-1][p] = tanh(mag[x+k][y] - mag[x][y]), k=1..5 (valid when x+k < SX)
// TH[k-1][p] = tanh(mag[x][y+k] - mag[x][y]), k=1..5 (valid when y+k < SY)
// Negative taps are recovered via exact odd symmetry of __ocml_tanh_f64.
__global__ void k_tanh(const float* __restrict__ mag, float* __restrict__ TV,
                       float* __restrict__ TH) {
#pragma clang fp contract(off)
    int yi = blockIdx.x * blockDim.x + threadIdx.x;
    int xi = blockIdx.y;
    int b  = blockIdx.z;
    size_t base = (size_t)b * SX * SY;
    size_t idx  = base + (size_t)xi * SY + yi;
    float cm = mag[idx];
#pragma unroll
    for (int k = 1; k <= 5; ++k) {
        if (xi + k < SX) {
            float nm = mag[idx + (size_t)k * SY];
            TV[(size_t)(k - 1) * NPIX + idx] = (float)tanh((double)(nm - cm));
        }
    }
#pragma unroll
    for (int k = 1; k <= 5; ++k) {
        if (yi + k < SY) {
            float nm = mag[idx + k];
            TH[(size_t)(k - 1) * NPIX + idx] = (float)tanh((double)(nm - cm));
        }
    }
}

// Stage 3 (fast): one ETF smoothing pass using precomputed tanh fields.
__global__ void k_etf_fast(const float2* __restrict__ tsrc, float2* __restrict__ tdst,
                           const float* __restrict__ T, int vert) {
#pragma clang fp contract(off)
    int yi = blockIdx.x * blockDim.x + threadIdx.x;
    int xi = blockIdx.y;
    int b  = blockIdx.z;
    size_t base = (size_t)b * SX * SY;
    size_t idx  = base + (size_t)xi * SY + yi;

    float2 ct = tsrc[idx];
    int ci      = vert ? xi : yi;          // varying coordinate
    int estride = vert ? SY : 1;           // element stride of a tap

    float sx = 0.0f, sy = 0.0f;
#pragma unroll
    for (int k = -MU; k <= MU; ++k) {
        int nc = ci + k;
        if (nc < 0 || nc >= SX) continue;  // SX == SY
        size_t nidx = idx + (size_t)k * estride;
        float2 nt = tsrc[nidx];
        float th;
        if (k > 0)      th =  T[(size_t)(k - 1) * NPIX + idx];
        else if (k < 0) th = -T[(size_t)(-k - 1) * NPIX + nidx];
        else            th =  0.0f;
        float dot = (ct.x * nt.x) + (ct.y * nt.y);
        float w   = ((th + 1.0f) * dot) * 0.5f;
        sx = sx + (nt.x * w);
        sy = sy + (nt.y * w);
    }
    float n = sqrtf((sx * sx) + (sy * sy));
    float d = (n == 0.0f) ? 1.0f : n;
    tdst[idx] = make_float2(sx / d, sy / d);
}

// Stage 3 (fallback, inline tanh) — used only if workspace is too small.
__global__ void k_etf(const float2* __restrict__ tsrc, float2* __restrict__ tdst,
                      const float* __restrict__ mag, int vert) {
#pragma clang fp contract(off)
    int yi = blockIdx.x * blockDim.x + threadIdx.x;
    int xi = blockIdx.y;
    int b  = blockIdx.z;
    size_t base = (size_t)b * SX * SY;
    size_t idx  = base + (size_t)xi * SY + yi;

    float  cm = mag[idx];
    float2 ct = tsrc[idx];

    float sx = 0.0f, sy = 0.0f;
    for (int k = -MU; k <= MU; ++k) {
        int nx = xi + (vert ? k : 0);
        int ny = yi + (vert ? 0 : k);
        if (nx < 0 || nx >= SX || ny < 0 || ny >= SY) continue;
        size_t nidx = base + (size_t)nx * SY + ny;
        float  nm = mag[nidx];
        float2 nt = tsrc[nidx];
        float dot = (ct.x * nt.x) + (ct.y * nt.y);
        float th  = (float)tanh((double)(nm - cm));
        float w   = ((th + 1.0f) * dot) * 0.5f;
        sx = sx + (nt.x * w);
        sy = sy + (nt.y * w);
    }
    float n = sqrtf((sx * sx) + (sy * sy));
    float d = (n == 0.0f) ? 1.0f : n;
    tdst[idx] = make_float2(sx / d, sy / d);
}

// Stage 4: DoG along the perpendicular of the ETF
__global__ void k_dog(const float* __restrict__ img, const float2* __restrict__ etf,
                      float* __restrict__ dog, DogW w) {
#pragma clang fp contract(off)
    int yi = blockIdx.x * blockDim.x + threadIdx.x;
    int xi = blockIdx.y;
    int b  = blockIdx.z;
    size_t base = (size_t)b * SX * SY;
    size_t idx  = base + (size_t)xi * SY + yi;

    float2 e = etf[idx];
    float perx = -e.y;
    float pery =  e.x;
    float xf = (float)xi, yf = (float)yi;

    float acc = 0.0f;
#pragma unroll
    for (int t = -3; t <= 3; ++t) {
        float tf  = (float)t;
        float ptx = xf + (perx * tf);
        float pty = yf + (pery * tf);
        int px = (int)rintf(fminf(fmaxf(ptx, 0.0f), (float)(SX - 1)));
        int py = (int)rintf(fminf(fmaxf(pty, 0.0f), (float)(SY - 1)));
        float il = img[base + (size_t)px * SY + py];
        acc = acc + (il * w.g[t + 3]);
    }
    dog[idx] = acc / w.tw;
}

// Stage 5: FDoG trace along the flow + tanh threshold -> int32 edges
__global__ void k_fdog(const float* __restrict__ dog, const float2* __restrict__ etf,
                       int* __restrict__ out, FdogW w) {
#pragma clang fp contract(off)
    int yi = blockIdx.x * blockDim.x + threadIdx.x;
    int xi = blockIdx.y;
    int b  = blockIdx.z;
    size_t base = (size_t)b * SX * SY;
    size_t idx  = base + (size_t)xi * SY + yi;

    float acc = 0.0f;

    int px = xi, py = yi;
    for (int s = 1; s <= 9; ++s) {
        float2 e = etf[base + (size_t)px * SY + py];
        float fx = (float)px + (e.x * -1.0f);
        float fy = (float)py + (e.y * -1.0f);
        px = (int)rintf(fminf(fmaxf(fx, 0.0f), (float)(SX - 1)));
        py = (int)rintf(fminf(fmaxf(fy, 0.0f), (float)(SY - 1)));
        acc = acc + (dog[base + (size_t)px * SY + py] * w.g[s]);
    }

    px = xi; py = yi;
    acc = acc + (dog[base + (size_t)px * SY + py] * w.g[0]);
    for (int s = 1; s <= 9; ++s) {
        float2 e = etf[base + (size_t)px * SY + py];
        float fx = (float)px + (e.x * 1.0f);
        float fy = (float)py + (e.y * 1.0f);
        px = (int)rintf(fminf(fmaxf(fx, 0.0f), (float)(SX - 1)));
        py = (int)rintf(fminf(fmaxf(fy, 0.0f), (float)(SY - 1)));
        acc = acc + (dog[base + (size_t)px * SY + py] * w.g[s]);
    }

    float fv = acc / w.tw;
    float th = 1.0f + (float)tanh((double)fv);
    out[idx] = ((fv < 0.0f) && (th < 0.7f)) ? 0 : 1;
}

static double gpdf(double v, double sig) {
    return exp(-(v * v) / (2.0 * sig * sig)) / (sqrt(2.0 * M_PI) * sig);
}

extern "C" void kernel_launch(void* const* d_in, const int* in_sizes, int n_in,
                              void* d_out, int out_size, void* d_ws, size_t ws_size,
                              hipStream_t stream) {
    const float* img = (const float*)d_in[0];
    int* out = (int*)d_out;
    char* ws = (char*)d_ws;

    // Fast-path workspace layout (60 MB + 4 B):
    //   mag:  [0, 4MB)      fp32 NPIX
    //   tA:   [4MB, 12MB)   float2 NPIX
    //   tB:   [12MB, 20MB)  float2 NPIX  (dog aliases this after ETF)
    //   TV:   [20MB, 40MB)  5 planes fp32 NPIX
    //   TH:   [40MB, 60MB)  5 planes fp32 NPIX
    //   maxbits: [60MB, 60MB+4)
    const size_t need = (size_t)60 * MB + 4;
    bool fast = ws_size >= need;

    float*  mag = (float*)(ws);
    float2* tA  = (float2*)(ws + (size_t)4  * MB);
    float2* tB  = (float2*)(ws + (size_t)12 * MB);
    float*  dog = (float*)(ws + (size_t)12 * MB);
    float*  TV  = (float*)(ws + (size_t)20 * MB);
    float*  TH  = (float*)(ws + (size_t)40 * MB);
    unsigned int* maxbits = (unsigned int*)(ws + (fast ? (size_t)60 * MB : (size_t)20 * MB));

    hipMemsetAsync(maxbits, 0, sizeof(unsigned int), stream);

    dim3 blk(256, 1, 1);
    dim3 grd(SY / 256, SX, BN);

    k_sobel<<<grd, blk, 0, stream>>>(img, mag, tA, maxbits);
    k_norm<<<NPIX / 256, 256, 0, stream>>>(mag, maxbits);

    float2* src = tA;
    float2* dst = tB;
    if (fast) {
        k_tanh<<<grd, blk, 0, stream>>>(mag, TV, TH);
        for (int it = 0; it < 3; ++it) {
            k_etf_fast<<<grd, blk, 0, stream>>>(src, dst, TV, 1);
            { float2* t = src; src = dst; dst = t; }
            k_etf_fast<<<grd, blk, 0, stream>>>(src, dst, TH, 0);
            { float2* t = src; src = dst; dst = t; }
        }
    } else {
        for (int it = 0; it < 3; ++it) {
            k_etf<<<grd, blk, 0, stream>>>(src, dst, mag, 1);
            { float2* t = src; src = dst; dst = t; }
            k_etf<<<grd, blk, 0, stream>>>(src, dst, mag, 0);
            { float2* t = src; src = dst; dst = t; }
        }
    }
    // src holds the final ETF; tB's slot is free for dog.
    float* dogbuf = (src == tA) ? dog : (float*)tA;

    DogW dw;
    {
        double tw = 0.0;
        for (int t = -3; t <= 3; ++t) {
            double g = gpdf((double)t, 1.0) - 0.99 * gpdf((double)t, 1.6);
            dw.g[t + 3] = (float)g;
            tw += g;
        }
        dw.tw = (float)tw;
    }
    k_dog<<<grd, blk, 0, stream>>>(img, src, dogbuf, dw);

    FdogW fw;
    {
        for (int s = 0; s <= 9; ++s) fw.g[s] = (float)gpdf((double)s, 3.0);
        double tw = 0.0;
        for (int s = 1; s <= 9; ++s) tw += gpdf((double)s, 3.0);
        for (int s = 0; s <= 9; ++s) tw += gpdf((double)s, 3.0);
        fw.tw = (float)tw;
    }
    k_fdog<<<grd, blk, 0, stream>>>(dogbuf, src, out, fw);
}

// Round 3
// 244.618 us; speedup vs baseline: 2.0443x; 1.1680x over previous
//
#include <hip/hip_runtime.h>
#include <math.h>

#pragma clang fp contract(off)

#define BN 4
#define SX 512
#define SY 512
#define NPIX (BN * SX * SY)
#define MU 5
#define MB (1024 * 1024)

struct DogW  { float g[7];  float tw; };
struct FdogW { float g[10]; float tw; };

// tanh via expm1 identity: tanh(d) = expm1(2|d|) / (expm1(2|d|) + 2), odd.
// ~1.6 ulp f64 vs ocml tanh's ~0.5 — after f32 cast, matches the reference
// chain (f64 tanh -> f32) except w/ prob ~8e-9 per eval.
__device__ __forceinline__ float fast_tanh_f32(float dF) {
    double d = (double)dF;
    double y = fabs(d);
    double t = expm1(2.0 * y);
    double r = t / (t + 2.0);
    if (y > 350.0) r = 1.0;   // avoid inf/inf (unreachable for our data; cheap guard)
    return (float)copysign(r, d);
}

__device__ __forceinline__ float img_at(const float* __restrict__ img, int b, int x, int y) {
    if (x < 0 || x >= SX || y < 0 || y >= SY) return 0.0f;
    return img[(size_t)b * SX * SY + (size_t)x * SY + y];
}

// Stage 1: Sobel -> mag (unnormalized), initial tangent field, global max(mag)
__global__ void k_sobel(const float* __restrict__ img, float* __restrict__ mag,
                        float2* __restrict__ tang, unsigned int* __restrict__ maxbits) {
#pragma clang fp contract(off)
    int yi = blockIdx.x * blockDim.x + threadIdx.x;
    int xi = blockIdx.y;
    int b  = blockIdx.z;

    float v00 = img_at(img, b, xi - 1, yi - 1);
    float v01 = img_at(img, b, xi - 1, yi    );
    float v02 = img_at(img, b, xi - 1, yi + 1);
    float v10 = img_at(img, b, xi,     yi - 1);
    float v12 = img_at(img, b, xi,     yi + 1);
    float v20 = img_at(img, b, xi + 1, yi - 1);
    float v21 = img_at(img, b, xi + 1, yi    );
    float v22 = img_at(img, b, xi + 1, yi + 1);

    float s0 = (-1.0f * v00);
    s0 = s0 + (-2.0f * v01);
    s0 = s0 + (-1.0f * v02);
    s0 = s0 + ( 1.0f * v20);
    s0 = s0 + ( 2.0f * v21);
    s0 = s0 + ( 1.0f * v22);
    float s1 = (-1.0f * v00);
    s1 = s1 + ( 1.0f * v02);
    s1 = s1 + (-2.0f * v10);
    s1 = s1 + ( 2.0f * v12);
    s1 = s1 + (-1.0f * v20);
    s1 = s1 + ( 1.0f * v22);

    float m = sqrtf((s0 * s0) + (s1 * s1));
    size_t idx = (size_t)b * SX * SY + (size_t)xi * SY + yi;
    mag[idx] = m;

    float tx = -s1, ty = s0;
    float n = sqrtf((tx * tx) + (ty * ty));
    float d = (n == 0.0f) ? 1.0f : n;
    tang[idx] = make_float2(tx / d, ty / d);

    __shared__ float red[256];
    red[threadIdx.x] = m;
    __syncthreads();
    for (int s = 128; s > 0; s >>= 1) {
        if ((int)threadIdx.x < s) red[threadIdx.x] = fmaxf(red[threadIdx.x], red[threadIdx.x + s]);
        __syncthreads();
    }
    if (threadIdx.x == 0) atomicMax(maxbits, __float_as_uint(red[0]));
}

// Stage 2: mag /= max(mag)
__global__ void k_norm(float* __restrict__ mag, const unsigned int* __restrict__ maxbits) {
    int i = blockIdx.x * blockDim.x + threadIdx.x;
    float mx = __uint_as_float(*maxbits);
    mag[i] = mag[i] / mx;
}

// Precompute tanh difference fields once (mag constant across all ETF iters).
// TV[k-1][p] = tanh(mag[x+k][y] - mag[x][y]), k=1..5
// TH[k-1][p] = tanh(mag[x][y+k] - mag[x][y]), k=1..5
// Negative taps recovered via exact odd symmetry.
__global__ void k_tanh(const float* __restrict__ mag, float* __restrict__ TV,
                       float* __restrict__ TH) {
#pragma clang fp contract(off)
    int yi = blockIdx.x * blockDim.x + threadIdx.x;
    int xi = blockIdx.y;
    int b  = blockIdx.z;
    size_t base = (size_t)b * SX * SY;
    size_t idx  = base + (size_t)xi * SY + yi;
    float cm = mag[idx];
#pragma unroll
    for (int k = 1; k <= 5; ++k) {
        if (xi + k < SX) {
            float nm = mag[idx + (size_t)k * SY];
            TV[(size_t)(k - 1) * NPIX + idx] = fast_tanh_f32(nm - cm);
        }
    }
#pragma unroll
    for (int k = 1; k <= 5; ++k) {
        if (yi + k < SY) {
            float nm = mag[idx + k];
            TH[(size_t)(k - 1) * NPIX + idx] = fast_tanh_f32(nm - cm);
        }
    }
}

// Stage 3a: V-pass, LDS-tiled. Block = 32(y) x 8(x) outputs; stage 18 rows of
// tsrc (x0-5 .. x0+12) so each tap comes from LDS (2.25 global loads/px vs 11).
// Arithmetic and tap order identical to the reference -> bit-exact.
#define VTY 32
#define VTX 8
__global__ __launch_bounds__(256) void k_etf_v(const float2* __restrict__ tsrc,
                                               float2* __restrict__ tdst,
                                               const float* __restrict__ TV) {
#pragma clang fp contract(off)
    int ty = threadIdx.x;              // 0..31 (y)
    int tx = threadIdx.y;              // 0..7  (x)
    int y0 = blockIdx.x * VTY;
    int x0 = blockIdx.y * VTX;
    int b  = blockIdx.z;
    int yi = y0 + ty;
    int xi = x0 + tx;
    size_t base = (size_t)b * SX * SY;
    size_t idx  = base + (size_t)xi * SY + yi;

    __shared__ float2 sT[VTX + 2 * MU][VTY];
    for (int r = tx; r < VTX + 2 * MU; r += VTX) {
        int gx = x0 - MU + r;
        if (gx >= 0 && gx < SX)
            sT[r][ty] = tsrc[base + (size_t)gx * SY + yi];
    }
    __syncthreads();

    float2 ct = sT[tx + MU][ty];

    float sx = 0.0f, sy = 0.0f;
#pragma unroll
    for (int k = -MU; k <= MU; ++k) {
        int nx = xi + k;
        if (nx < 0 || nx >= SX) continue;
        float2 nt = sT[tx + MU + k][ty];
        float th;
        if (k > 0)      th =  TV[(size_t)(k - 1) * NPIX + idx];
        else if (k < 0) th = -TV[(size_t)(-k - 1) * NPIX + (idx + (size_t)k * SY)];
        else            th =  0.0f;
        float dot = (ct.x * nt.x) + (ct.y * nt.y);
        float w   = ((th + 1.0f) * dot) * 0.5f;
        sx = sx + (nt.x * w);
        sy = sy + (nt.y * w);
    }
    float n = sqrtf((sx * sx) + (sy * sy));
    float d = (n == 0.0f) ? 1.0f : n;
    tdst[idx] = make_float2(sx / d, sy / d);
}

// Stage 3b: H-pass (row-contiguous taps; L1 serves the 11x reuse).
__global__ void k_etf_h(const float2* __restrict__ tsrc, float2* __restrict__ tdst,
                        const float* __restrict__ TH) {
#pragma clang fp contract(off)
    int yi = blockIdx.x * blockDim.x + threadIdx.x;
    int xi = blockIdx.y;
    int b  = blockIdx.z;
    size_t base = (size_t)b * SX * SY;
    size_t idx  = base + (size_t)xi * SY + yi;

    float2 ct = tsrc[idx];

    float sx = 0.0f, sy = 0.0f;
#pragma unroll
    for (int k = -MU; k <= MU; ++k) {
        int ny = yi + k;
        if (ny < 0 || ny >= SY) continue;
        size_t nidx = idx + k;
        float2 nt = tsrc[nidx];
        float th;
        if (k > 0)      th =  TH[(size_t)(k - 1) * NPIX + idx];
        else if (k < 0) th = -TH[(size_t)(-k - 1) * NPIX + nidx];
        else            th =  0.0f;
        float dot = (ct.x * nt.x) + (ct.y * nt.y);
        float w   = ((th + 1.0f) * dot) * 0.5f;
        sx = sx + (nt.x * w);
        sy = sy + (nt.y * w);
    }
    float n = sqrtf((sx * sx) + (sy * sy));
    float d = (n == 0.0f) ? 1.0f : n;
    tdst[idx] = make_float2(sx / d, sy / d);
}

// Stage 3 (fallback, inline ocml tanh) — used only if workspace is too small.
__global__ void k_etf(const float2* __restrict__ tsrc, float2* __restrict__ tdst,
                      const float* __restrict__ mag, int vert) {
#pragma clang fp contract(off)
    int yi = blockIdx.x * blockDim.x + threadIdx.x;
    int xi = blockIdx.y;
    int b  = blockIdx.z;
    size_t base = (size_t)b * SX * SY;
    size_t idx  = base + (size_t)xi * SY + yi;

    float  cm = mag[idx];
    float2 ct = tsrc[idx];

    float sx = 0.0f, sy = 0.0f;
    for (int k = -MU; k <= MU; ++k) {
        int nx = xi + (vert ? k : 0);
        int ny = yi + (vert ? 0 : k);
        if (nx < 0 || nx >= SX || ny < 0 || ny >= SY) continue;
        size_t nidx = base + (size_t)nx * SY + ny;
        float  nm = mag[nidx];
        float2 nt = tsrc[nidx];
        float dot = (ct.x * nt.x) + (ct.y * nt.y);
        float th  = (float)tanh((double)(nm - cm));
        float w   = ((th + 1.0f) * dot) * 0.5f;
        sx = sx + (nt.x * w);
        sy = sy + (nt.y * w);
    }
    float n = sqrtf((sx * sx) + (sy * sy));
    float d = (n == 0.0f) ? 1.0f : n;
    tdst[idx] = make_float2(sx / d, sy / d);
}

// Stage 4: DoG along the perpendicular of the ETF
__global__ void k_dog(const float* __restrict__ img, const float2* __restrict__ etf,
                      float* __restrict__ dog, DogW w) {
#pragma clang fp contract(off)
    int yi = blockIdx.x * blockDim.x + threadIdx.x;
    int xi = blockIdx.y;
    int b  = blockIdx.z;
    size_t base = (size_t)b * SX * SY;
    size_t idx  = base + (size_t)xi * SY + yi;

    float2 e = etf[idx];
    float perx = -e.y;
    float pery =  e.x;
    float xf = (float)xi, yf = (float)yi;

    float acc = 0.0f;
#pragma unroll
    for (int t = -3; t <= 3; ++t) {
        float tf  = (float)t;
        float ptx = xf + (perx * tf);
        float pty = yf + (pery * tf);
        int px = (int)rintf(fminf(fmaxf(ptx, 0.0f), (float)(SX - 1)));
        int py = (int)rintf(fminf(fmaxf(pty, 0.0f), (float)(SY - 1)));
        float il = img[base + (size_t)px * SY + py];
        acc = acc + (il * w.g[t + 3]);
    }
    dog[idx] = acc / w.tw;
}

// Stage 5: FDoG trace along the flow + tanh threshold -> int32 edges
__global__ void k_fdog(const float* __restrict__ dog, const float2* __restrict__ etf,
                       int* __restrict__ out, FdogW w) {
#pragma clang fp contract(off)
    int yi = blockIdx.x * blockDim.x + threadIdx.x;
    int xi = blockIdx.y;
    int b  = blockIdx.z;
    size_t base = (size_t)b * SX * SY;
    size_t idx  = base + (size_t)xi * SY + yi;

    float acc = 0.0f;

    int px = xi, py = yi;
    for (int s = 1; s <= 9; ++s) {
        float2 e = etf[base + (size_t)px * SY + py];
        float fx = (float)px + (e.x * -1.0f);
        float fy = (float)py + (e.y * -1.0f);
        px = (int)rintf(fminf(fmaxf(fx, 0.0f), (float)(SX - 1)));
        py = (int)rintf(fminf(fmaxf(fy, 0.0f), (float)(SY - 1)));
        acc = acc + (dog[base + (size_t)px * SY + py] * w.g[s]);
    }

    px = xi; py = yi;
    acc = acc + (dog[base + (size_t)px * SY + py] * w.g[0]);
    for (int s = 1; s <= 9; ++s) {
        float2 e = etf[base + (size_t)px * SY + py];
        float fx = (float)px + (e.x * 1.0f);
        float fy = (float)py + (e.y * 1.0f);
        px = (int)rintf(fminf(fmaxf(fx, 0.0f), (float)(SX - 1)));
        py = (int)rintf(fminf(fmaxf(fy, 0.0f), (float)(SY - 1)));
        acc = acc + (dog[base + (size_t)px * SY + py] * w.g[s]);
    }

    float fv = acc / w.tw;
    float th = 1.0f + fast_tanh_f32(fv);
    out[idx] = ((fv < 0.0f) && (th < 0.7f)) ? 0 : 1;
}

static double gpdf(double v, double sig) {
    return exp(-(v * v) / (2.0 * sig * sig)) / (sqrt(2.0 * M_PI) * sig);
}

extern "C" void kernel_launch(void* const* d_in, const int* in_sizes, int n_in,
                              void* d_out, int out_size, void* d_ws, size_t ws_size,
                              hipStream_t stream) {
    const float* img = (const float*)d_in[0];
    int* out = (int*)d_out;
    char* ws = (char*)d_ws;

    // Fast-path workspace layout (60 MB + 4 B):
    //   mag [0,4MB) | tA [4,12) | tB [12,20) (dog aliases) | TV [20,40) | TH [40,60) | maxbits
    const size_t need = (size_t)60 * MB + 4;
    bool fast = ws_size >= need;

    float*  mag = (float*)(ws);
    float2* tA  = (float2*)(ws + (size_t)4  * MB);
    float2* tB  = (float2*)(ws + (size_t)12 * MB);
    float*  dog = (float*)(ws + (size_t)12 * MB);
    float*  TV  = (float*)(ws + (size_t)20 * MB);
    float*  TH  = (float*)(ws + (size_t)40 * MB);
    unsigned int* maxbits = (unsigned int*)(ws + (fast ? (size_t)60 * MB : (size_t)20 * MB));

    hipMemsetAsync(maxbits, 0, sizeof(unsigned int), stream);

    dim3 blk(256, 1, 1);
    dim3 grd(SY / 256, SX, BN);
    dim3 vblk(VTY, VTX, 1);
    dim3 vgrd(SY / VTY, SX / VTX, BN);

    k_sobel<<<grd, blk, 0, stream>>>(img, mag, tA, maxbits);
    k_norm<<<NPIX / 256, 256, 0, stream>>>(mag, maxbits);

    float2* src = tA;
    float2* dst = tB;
    if (fast) {
        k_tanh<<<grd, blk, 0, stream>>>(mag, TV, TH);
        for (int it = 0; it < 3; ++it) {
            k_etf_v<<<vgrd, vblk, 0, stream>>>(src, dst, TV);
            { float2* t = src; src = dst; dst = t; }
            k_etf_h<<<grd, blk, 0, stream>>>(src, dst, TH);
            { float2* t = src; src = dst; dst = t; }
        }
    } else {
        for (int it = 0; it < 3; ++it) {
            k_etf<<<grd, blk, 0, stream>>>(src, dst, mag, 1);
            { float2* t = src; src = dst; dst = t; }
            k_etf<<<grd, blk, 0, stream>>>(src, dst, mag, 0);
            { float2* t = src; src = dst; dst = t; }
        }
    }
    float* dogbuf = (src == tA) ? dog : (float*)tA;

    DogW dw;
    {
        double tw = 0.0;
        for (int t = -3; t <= 3; ++t) {
            double g = gpdf((double)t, 1.0) - 0.99 * gpdf((double)t, 1.6);
            dw.g[t + 3] = (float)g;
            tw += g;
        }
        dw.tw = (float)tw;
    }
    k_dog<<<grd, blk, 0, stream>>>(img, src, dogbuf, dw);

    FdogW fw;
    {
        for (int s = 0; s <= 9; ++s) fw.g[s] = (float)gpdf((double)s, 3.0);
        double tw = 0.0;
        for (int s = 1; s <= 9; ++s) tw += gpdf((double)s, 3.0);
        for (int s = 0; s <= 9; ++s) tw += gpdf((double)s, 3.0);
        fw.tw = (float)tw;
    }
    k_fdog<<<grd, blk, 0, stream>>>(dogbuf, src, out, fw);
}

// Round 4
// 203.116 us; speedup vs baseline: 2.4620x; 1.2043x over previous
//
#include <hip/hip_runtime.h>
#include <math.h>

#pragma clang fp contract(off)

#define BN 4
#define SX 512
#define SY 512
#define NPIX (BN * SX * SY)
#define MU 5
#define MB (1024 * 1024)
#define NBLOCKS 4096   // (SY/256) * SX * BN

struct DogW  { float g[7];  float tw; };
struct FdogW { float g[10]; float tw; };

// tanh via expm1 identity: tanh(d) = expm1(2|d|) / (expm1(2|d|) + 2), odd.
__device__ __forceinline__ float fast_tanh_f32(float dF) {
    double d = (double)dF;
    double y = fabs(d);
    double t = expm1(2.0 * y);
    double r = t / (t + 2.0);
    if (y > 350.0) r = 1.0;
    return (float)copysign(r, d);
}

__device__ __forceinline__ float img_at(const float* __restrict__ img, int b, int x, int y) {
    if (x < 0 || x >= SX || y < 0 || y >= SY) return 0.0f;
    return img[(size_t)b * SX * SY + (size_t)x * SY + y];
}

// Stage 1: Sobel -> mag (unnormalized), initial tangent field, per-block max.
// No global atomics: wave shuffle reduce + one plain store per block.
__global__ void k_sobel(const float* __restrict__ img, float* __restrict__ mag,
                        float2* __restrict__ tang, float* __restrict__ partial) {
#pragma clang fp contract(off)
    int yi = blockIdx.x * blockDim.x + threadIdx.x;
    int xi = blockIdx.y;
    int b  = blockIdx.z;

    float v00 = img_at(img, b, xi - 1, yi - 1);
    float v01 = img_at(img, b, xi - 1, yi    );
    float v02 = img_at(img, b, xi - 1, yi + 1);
    float v10 = img_at(img, b, xi,     yi - 1);
    float v12 = img_at(img, b, xi,     yi + 1);
    float v20 = img_at(img, b, xi + 1, yi - 1);
    float v21 = img_at(img, b, xi + 1, yi    );
    float v22 = img_at(img, b, xi + 1, yi + 1);

    float s0 = (-1.0f * v00);
    s0 = s0 + (-2.0f * v01);
    s0 = s0 + (-1.0f * v02);
    s0 = s0 + ( 1.0f * v20);
    s0 = s0 + ( 2.0f * v21);
    s0 = s0 + ( 1.0f * v22);
    float s1 = (-1.0f * v00);
    s1 = s1 + ( 1.0f * v02);
    s1 = s1 + (-2.0f * v10);
    s1 = s1 + ( 2.0f * v12);
    s1 = s1 + (-1.0f * v20);
    s1 = s1 + ( 1.0f * v22);

    float m = sqrtf((s0 * s0) + (s1 * s1));
    size_t idx = (size_t)b * SX * SY + (size_t)xi * SY + yi;
    mag[idx] = m;

    float tx = -s1, ty = s0;
    float n = sqrtf((tx * tx) + (ty * ty));
    float d = (n == 0.0f) ? 1.0f : n;
    tang[idx] = make_float2(tx / d, ty / d);

    // wave-level max, then 4 partials in LDS, then one store per block
    float wm = m;
    for (int off = 32; off > 0; off >>= 1) wm = fmaxf(wm, __shfl_down(wm, off, 64));
    __shared__ float red[4];
    int lane = threadIdx.x & 63;
    int wid  = threadIdx.x >> 6;
    if (lane == 0) red[wid] = wm;
    __syncthreads();
    if (threadIdx.x == 0) {
        float bm = fmaxf(fmaxf(red[0], red[1]), fmaxf(red[2], red[3]));
        int bid = blockIdx.x + gridDim.x * (blockIdx.y + gridDim.y * blockIdx.z);
        partial[bid] = bm;
    }
}

// Stage 2: reduce 4096 per-block partials -> global max bits (one block).
__global__ void k_reduce(const float* __restrict__ partial, unsigned int* __restrict__ maxbits) {
    float m = 0.0f;
    for (int i = threadIdx.x; i < NBLOCKS; i += 256) m = fmaxf(m, partial[i]);
    for (int off = 32; off > 0; off >>= 1) m = fmaxf(m, __shfl_down(m, off, 64));
    __shared__ float red[4];
    int lane = threadIdx.x & 63;
    int wid  = threadIdx.x >> 6;
    if (lane == 0) red[wid] = m;
    __syncthreads();
    if (threadIdx.x == 0) {
        float bm = fmaxf(fmaxf(red[0], red[1]), fmaxf(red[2], red[3]));
        *maxbits = __float_as_uint(bm);
    }
}

// Stage 2b (fallback only): mag /= max(mag)
__global__ void k_norm(float* __restrict__ mag, const unsigned int* __restrict__ maxbits) {
    int i = blockIdx.x * blockDim.x + threadIdx.x;
    float mx = __uint_as_float(*maxbits);
    mag[i] = mag[i] / mx;
}

// Precompute tanh difference fields; normalization fused (mag[p]/mx is the
// identical single-rounded IEEE div the reference's mag/max pass performs).
// TV[k-1][p] = tanh(magN[x+k][y] - magN[x][y]), k=1..5
// TH[k-1][p] = tanh(magN[x][y+k] - magN[x][y]), k=1..5
__global__ void k_tanh(const float* __restrict__ mag, const unsigned int* __restrict__ maxbits,
                       float* __restrict__ TV, float* __restrict__ TH) {
#pragma clang fp contract(off)
    int yi = blockIdx.x * blockDim.x + threadIdx.x;
    int xi = blockIdx.y;
    int b  = blockIdx.z;
    size_t base = (size_t)b * SX * SY;
    size_t idx  = base + (size_t)xi * SY + yi;
    float mx = __uint_as_float(*maxbits);
    float cm = mag[idx] / mx;
#pragma unroll
    for (int k = 1; k <= 5; ++k) {
        if (xi + k < SX) {
            float nm = mag[idx + (size_t)k * SY] / mx;
            TV[(size_t)(k - 1) * NPIX + idx] = fast_tanh_f32(nm - cm);
        }
    }
#pragma unroll
    for (int k = 1; k <= 5; ++k) {
        if (yi + k < SY) {
            float nm = mag[idx + k] / mx;
            TH[(size_t)(k - 1) * NPIX + idx] = fast_tanh_f32(nm - cm);
        }
    }
}

// Stage 3a: V-pass, LDS-tiled (18 rows staged; 2.25 global loads/px vs 11).
#define VTY 32
#define VTX 8
__global__ __launch_bounds__(256) void k_etf_v(const float2* __restrict__ tsrc,
                                               float2* __restrict__ tdst,
                                               const float* __restrict__ TV) {
#pragma clang fp contract(off)
    int ty = threadIdx.x;
    int tx = threadIdx.y;
    int y0 = blockIdx.x * VTY;
    int x0 = blockIdx.y * VTX;
    int b  = blockIdx.z;
    int yi = y0 + ty;
    int xi = x0 + tx;
    size_t base = (size_t)b * SX * SY;
    size_t idx  = base + (size_t)xi * SY + yi;

    __shared__ float2 sT[VTX + 2 * MU][VTY];
    for (int r = tx; r < VTX + 2 * MU; r += VTX) {
        int gx = x0 - MU + r;
        if (gx >= 0 && gx < SX)
            sT[r][ty] = tsrc[base + (size_t)gx * SY + yi];
    }
    __syncthreads();

    float2 ct = sT[tx + MU][ty];

    float sx = 0.0f, sy = 0.0f;
#pragma unroll
    for (int k = -MU; k <= MU; ++k) {
        int nx = xi + k;
        if (nx < 0 || nx >= SX) continue;
        float2 nt = sT[tx + MU + k][ty];
        float th;
        if (k > 0)      th =  TV[(size_t)(k - 1) * NPIX + idx];
        else if (k < 0) th = -TV[(size_t)(-k - 1) * NPIX + (idx + (size_t)k * SY)];
        else            th =  0.0f;
        float dot = (ct.x * nt.x) + (ct.y * nt.y);
        float w   = ((th + 1.0f) * dot) * 0.5f;
        sx = sx + (nt.x * w);
        sy = sy + (nt.y * w);
    }
    float n = sqrtf((sx * sx) + (sy * sy));
    float d = (n == 0.0f) ? 1.0f : n;
    tdst[idx] = make_float2(sx / d, sy / d);
}

// Stage 3b: H-pass (row-contiguous taps; L1 serves the 11x reuse).
__global__ void k_etf_h(const float2* __restrict__ tsrc, float2* __restrict__ tdst,
                        const float* __restrict__ TH) {
#pragma clang fp contract(off)
    int yi = blockIdx.x * blockDim.x + threadIdx.x;
    int xi = blockIdx.y;
    int b  = blockIdx.z;
    size_t base = (size_t)b * SX * SY;
    size_t idx  = base + (size_t)xi * SY + yi;

    float2 ct = tsrc[idx];

    float sx = 0.0f, sy = 0.0f;
#pragma unroll
    for (int k = -MU; k <= MU; ++k) {
        int ny = yi + k;
        if (ny < 0 || ny >= SY) continue;
        size_t nidx = idx + k;
        float2 nt = tsrc[nidx];
        float th;
        if (k > 0)      th =  TH[(size_t)(k - 1) * NPIX + idx];
        else if (k < 0) th = -TH[(size_t)(-k - 1) * NPIX + nidx];
        else            th =  0.0f;
        float dot = (ct.x * nt.x) + (ct.y * nt.y);
        float w   = ((th + 1.0f) * dot) * 0.5f;
        sx = sx + (nt.x * w);
        sy = sy + (nt.y * w);
    }
    float n = sqrtf((sx * sx) + (sy * sy));
    float d = (n == 0.0f) ? 1.0f : n;
    tdst[idx] = make_float2(sx / d, sy / d);
}

// Stage 3 (fallback, inline ocml tanh) — only if workspace is too small.
__global__ void k_etf(const float2* __restrict__ tsrc, float2* __restrict__ tdst,
                      const float* __restrict__ mag, int vert) {
#pragma clang fp contract(off)
    int yi = blockIdx.x * blockDim.x + threadIdx.x;
    int xi = blockIdx.y;
    int b  = blockIdx.z;
    size_t base = (size_t)b * SX * SY;
    size_t idx  = base + (size_t)xi * SY + yi;

    float  cm = mag[idx];
    float2 ct = tsrc[idx];

    float sx = 0.0f, sy = 0.0f;
    for (int k = -MU; k <= MU; ++k) {
        int nx = xi + (vert ? k : 0);
        int ny = yi + (vert ? 0 : k);
        if (nx < 0 || nx >= SX || ny < 0 || ny >= SY) continue;
        size_t nidx = base + (size_t)nx * SY + ny;
        float  nm = mag[nidx];
        float2 nt = tsrc[nidx];
        float dot = (ct.x * nt.x) + (ct.y * nt.y);
        float th  = (float)tanh((double)(nm - cm));
        float w   = ((th + 1.0f) * dot) * 0.5f;
        sx = sx + (nt.x * w);
        sy = sy + (nt.y * w);
    }
    float n = sqrtf((sx * sx) + (sy * sy));
    float d = (n == 0.0f) ? 1.0f : n;
    tdst[idx] = make_float2(sx / d, sy / d);
}

// Stage 4: DoG along the perpendicular of the ETF
__global__ void k_dog(const float* __restrict__ img, const float2* __restrict__ etf,
                      float* __restrict__ dog, DogW w) {
#pragma clang fp contract(off)
    int yi = blockIdx.x * blockDim.x + threadIdx.x;
    int xi = blockIdx.y;
    int b  = blockIdx.z;
    size_t base = (size_t)b * SX * SY;
    size_t idx  = base + (size_t)xi * SY + yi;

    float2 e = etf[idx];
    float perx = -e.y;
    float pery =  e.x;
    float xf = (float)xi, yf = (float)yi;

    float acc = 0.0f;
#pragma unroll
    for (int t = -3; t <= 3; ++t) {
        float tf  = (float)t;
        float ptx = xf + (perx * tf);
        float pty = yf + (pery * tf);
        int px = (int)rintf(fminf(fmaxf(ptx, 0.0f), (float)(SX - 1)));
        int py = (int)rintf(fminf(fmaxf(pty, 0.0f), (float)(SY - 1)));
        float il = img[base + (size_t)px * SY + py];
        acc = acc + (il * w.g[t + 3]);
    }
    dog[idx] = acc / w.tw;
}

// Stage 5: FDoG trace along the flow + tanh threshold -> int32 edges
__global__ void k_fdog(const float* __restrict__ dog, const float2* __restrict__ etf,
                       int* __restrict__ out, FdogW w) {
#pragma clang fp contract(off)
    int yi = blockIdx.x * blockDim.x + threadIdx.x;
    int xi = blockIdx.y;
    int b  = blockIdx.z;
    size_t base = (size_t)b * SX * SY;
    size_t idx  = base + (size_t)xi * SY + yi;

    float acc = 0.0f;

    int px = xi, py = yi;
    for (int s = 1; s <= 9; ++s) {
        float2 e = etf[base + (size_t)px * SY + py];
        float fx = (float)px + (e.x * -1.0f);
        float fy = (float)py + (e.y * -1.0f);
        px = (int)rintf(fminf(fmaxf(fx, 0.0f), (float)(SX - 1)));
        py = (int)rintf(fminf(fmaxf(fy, 0.0f), (float)(SY - 1)));
        acc = acc + (dog[base + (size_t)px * SY + py] * w.g[s]);
    }

    px = xi; py = yi;
    acc = acc + (dog[base + (size_t)px * SY + py] * w.g[0]);
    for (int s = 1; s <= 9; ++s) {
        float2 e = etf[base + (size_t)px * SY + py];
        float fx = (float)px + (e.x * 1.0f);
        float fy = (float)py + (e.y * 1.0f);
        px = (int)rintf(fminf(fmaxf(fx, 0.0f), (float)(SX - 1)));
        py = (int)rintf(fminf(fmaxf(fy, 0.0f), (float)(SY - 1)));
        acc = acc + (dog[base + (size_t)px * SY + py] * w.g[s]);
    }

    float fv = acc / w.tw;
    float th = 1.0f + fast_tanh_f32(fv);
    out[idx] = ((fv < 0.0f) && (th < 0.7f)) ? 0 : 1;
}

static double gpdf(double v, double sig) {
    return exp(-(v * v) / (2.0 * sig * sig)) / (sqrt(2.0 * M_PI) * sig);
}

extern "C" void kernel_launch(void* const* d_in, const int* in_sizes, int n_in,
                              void* d_out, int out_size, void* d_ws, size_t ws_size,
                              hipStream_t stream) {
    const float* img = (const float*)d_in[0];
    int* out = (int*)d_out;
    char* ws = (char*)d_ws;

    // Fast-path workspace layout (60 MB + 16 KB + 4 B):
    //   mag [0,4MB) | tA [4,12) | tB [12,20) (dog aliases) | TV [20,40) | TH [40,60)
    //   partial [60MB, 60MB+16KB) | maxbits [+4)
    const size_t need = (size_t)60 * MB + NBLOCKS * sizeof(float) + 4;
    bool fast = ws_size >= need;

    float*  mag = (float*)(ws);
    float2* tA  = (float2*)(ws + (size_t)4  * MB);
    float2* tB  = (float2*)(ws + (size_t)12 * MB);
    float*  dog = (float*)(ws + (size_t)12 * MB);
    float*  TV  = (float*)(ws + (size_t)20 * MB);
    float*  TH  = (float*)(ws + (size_t)40 * MB);
    size_t  tail = fast ? (size_t)60 * MB : (size_t)20 * MB;
    float*        partial = (float*)(ws + tail);
    unsigned int* maxbits = (unsigned int*)(ws + tail + NBLOCKS * sizeof(float));

    dim3 blk(256, 1, 1);
    dim3 grd(SY / 256, SX, BN);
    dim3 vblk(VTY, VTX, 1);
    dim3 vgrd(SY / VTY, SX / VTX, BN);

    k_sobel<<<grd, blk, 0, stream>>>(img, mag, tA, partial);
    k_reduce<<<1, 256, 0, stream>>>(partial, maxbits);

    float2* src = tA;
    float2* dst = tB;
    if (fast) {
        k_tanh<<<grd, blk, 0, stream>>>(mag, maxbits, TV, TH);
        for (int it = 0; it < 3; ++it) {
            k_etf_v<<<vgrd, vblk, 0, stream>>>(src, dst, TV);
            { float2* t = src; src = dst; dst = t; }
            k_etf_h<<<grd, blk, 0, stream>>>(src, dst, TH);
            { float2* t = src; src = dst; dst = t; }
        }
    } else {
        k_norm<<<NPIX / 256, 256, 0, stream>>>(mag, maxbits);
        for (int it = 0; it < 3; ++it) {
            k_etf<<<grd, blk, 0, stream>>>(src, dst, mag, 1);
            { float2* t = src; src = dst; dst = t; }
            k_etf<<<grd, blk, 0, stream>>>(src, dst, mag, 0);
            { float2* t = src; src = dst; dst = t; }
        }
    }
    float* dogbuf = (src == tA) ? dog : (float*)tA;

    DogW dw;
    {
        double tw = 0.0;
        for (int t = -3; t <= 3; ++t) {
            double g = gpdf((double)t, 1.0) - 0.99 * gpdf((double)t, 1.6);
            dw.g[t + 3] = (float)g;
            tw += g;
        }
        dw.tw = (float)tw;
    }
    k_dog<<<grd, blk, 0, stream>>>(img, src, dogbuf, dw);

    FdogW fw;
    {
        for (int s = 0; s <= 9; ++s) fw.g[s] = (float)gpdf((double)s, 3.0);
        double tw = 0.0;
        for (int s = 1; s <= 9; ++s) tw += gpdf((double)s, 3.0);
        for (int s = 0; s <= 9; ++s) tw += gpdf((double)s, 3.0);
        fw.tw = (float)tw;
    }
    k_fdog<<<grd, blk, 0, stream>>>(dogbuf, src, out, fw);
}

// Round 5
// 195.550 us; speedup vs baseline: 2.5573x; 1.0387x over previous
//
#include <hip/hip_runtime.h>
#include <math.h>

#pragma clang fp contract(off)

#define BN 4
#define SX 512
#define SY 512
#define NPIX (BN * SX * SY)
#define MU 5
#define MB (1024 * 1024)
#define NBLOCKS 4096   // (SY/256) * SX * BN

struct DogW  { float g[7];  float tw; };
struct FdogW { float g[10]; float tw; };

// tanh via expm1 identity: tanh(d) = expm1(2|d|) / (expm1(2|d|) + 2), odd.
__device__ __forceinline__ float fast_tanh_f32(float dF) {
    double d = (double)dF;
    double y = fabs(d);
    double t = expm1(2.0 * y);
    double r = t / (t + 2.0);
    if (y > 350.0) r = 1.0;
    return (float)copysign(r, d);
}

__device__ __forceinline__ float img_at(const float* __restrict__ img, int b, int x, int y) {
    if (x < 0 || x >= SX || y < 0 || y >= SY) return 0.0f;
    return img[(size_t)b * SX * SY + (size_t)x * SY + y];
}

// Stage 1: Sobel -> mag (unnormalized), initial tangent field, per-block max.
__global__ void k_sobel(const float* __restrict__ img, float* __restrict__ mag,
                        float2* __restrict__ tang, float* __restrict__ partial) {
#pragma clang fp contract(off)
    int yi = blockIdx.x * blockDim.x + threadIdx.x;
    int xi = blockIdx.y;
    int b  = blockIdx.z;

    float v00 = img_at(img, b, xi - 1, yi - 1);
    float v01 = img_at(img, b, xi - 1, yi    );
    float v02 = img_at(img, b, xi - 1, yi + 1);
    float v10 = img_at(img, b, xi,     yi - 1);
    float v12 = img_at(img, b, xi,     yi + 1);
    float v20 = img_at(img, b, xi + 1, yi - 1);
    float v21 = img_at(img, b, xi + 1, yi    );
    float v22 = img_at(img, b, xi + 1, yi + 1);

    float s0 = (-1.0f * v00);
    s0 = s0 + (-2.0f * v01);
    s0 = s0 + (-1.0f * v02);
    s0 = s0 + ( 1.0f * v20);
    s0 = s0 + ( 2.0f * v21);
    s0 = s0 + ( 1.0f * v22);
    float s1 = (-1.0f * v00);
    s1 = s1 + ( 1.0f * v02);
    s1 = s1 + (-2.0f * v10);
    s1 = s1 + ( 2.0f * v12);
    s1 = s1 + (-1.0f * v20);
    s1 = s1 + ( 1.0f * v22);

    float m = sqrtf((s0 * s0) + (s1 * s1));
    size_t idx = (size_t)b * SX * SY + (size_t)xi * SY + yi;
    mag[idx] = m;

    float tx = -s1, ty = s0;
    float n = sqrtf((tx * tx) + (ty * ty));
    float d = (n == 0.0f) ? 1.0f : n;
    tang[idx] = make_float2(tx / d, ty / d);

    float wm = m;
    for (int off = 32; off > 0; off >>= 1) wm = fmaxf(wm, __shfl_down(wm, off, 64));
    __shared__ float red[4];
    int lane = threadIdx.x & 63;
    int wid  = threadIdx.x >> 6;
    if (lane == 0) red[wid] = wm;
    __syncthreads();
    if (threadIdx.x == 0) {
        float bm = fmaxf(fmaxf(red[0], red[1]), fmaxf(red[2], red[3]));
        int bid = blockIdx.x + gridDim.x * (blockIdx.y + gridDim.y * blockIdx.z);
        partial[bid] = bm;
    }
}

// Stage 2: reduce per-block partials -> global max bits (one block).
__global__ void k_reduce(const float* __restrict__ partial, unsigned int* __restrict__ maxbits) {
    float m = 0.0f;
    for (int i = threadIdx.x; i < NBLOCKS; i += 256) m = fmaxf(m, partial[i]);
    for (int off = 32; off > 0; off >>= 1) m = fmaxf(m, __shfl_down(m, off, 64));
    __shared__ float red[4];
    int lane = threadIdx.x & 63;
    int wid  = threadIdx.x >> 6;
    if (lane == 0) red[wid] = m;
    __syncthreads();
    if (threadIdx.x == 0) {
        float bm = fmaxf(fmaxf(red[0], red[1]), fmaxf(red[2], red[3]));
        *maxbits = __float_as_uint(bm);
    }
}

// Stage 2b (fallback only): mag /= max(mag)
__global__ void k_norm(float* __restrict__ mag, const unsigned int* __restrict__ maxbits) {
    int i = blockIdx.x * blockDim.x + threadIdx.x;
    float mx = __uint_as_float(*maxbits);
    mag[i] = mag[i] / mx;
}

// Precompute tanh difference fields; normalization fused.
__global__ void k_tanh(const float* __restrict__ mag, const unsigned int* __restrict__ maxbits,
                       float* __restrict__ TV, float* __restrict__ TH) {
#pragma clang fp contract(off)
    int yi = blockIdx.x * blockDim.x + threadIdx.x;
    int xi = blockIdx.y;
    int b  = blockIdx.z;
    size_t base = (size_t)b * SX * SY;
    size_t idx  = base + (size_t)xi * SY + yi;
    float mx = __uint_as_float(*maxbits);
    float cm = mag[idx] / mx;
#pragma unroll
    for (int k = 1; k <= 5; ++k) {
        if (xi + k < SX) {
            float nm = mag[idx + (size_t)k * SY] / mx;
            TV[(size_t)(k - 1) * NPIX + idx] = fast_tanh_f32(nm - cm);
        }
    }
#pragma unroll
    for (int k = 1; k <= 5; ++k) {
        if (yi + k < SY) {
            float nm = mag[idx + k] / mx;
            TH[(size_t)(k - 1) * NPIX + idx] = fast_tanh_f32(nm - cm);
        }
    }
}

// Stage 3a: V-pass. Tile 32(y) x 8(x); stage tsrc (18 rows) AND the 13 needed
// TV row-segments per plane in LDS. All tap reads come from LDS; global reads
// are coalesced float4. Arithmetic identical to reference -> bit-exact.
#define VTY 32
#define VTX 8
__global__ __launch_bounds__(256) void k_etf_v(const float2* __restrict__ tsrc,
                                               float2* __restrict__ tdst,
                                               const float* __restrict__ TV) {
#pragma clang fp contract(off)
    int ty = threadIdx.x & 31;   // y within tile
    int tx = threadIdx.x >> 5;   // x row within tile (0..7)
    int y0 = blockIdx.x * VTY;
    int x0 = blockIdx.y * VTX;
    int b  = blockIdx.z;
    size_t base = (size_t)b * SX * SY;

    __shared__ __align__(16) float2 sT[VTX + 2 * MU][VTY];     // 18 x 32 (4.6 KB)
    __shared__ __align__(16) float  sTV[5][VTX + MU][VTY];     // 5 x 13 x 32 (8.3 KB)

    int tid = threadIdx.x;
    // stage tsrc rows x0-5 .. x0+12 : 18 rows * 16 float4
    for (int i = tid; i < (VTX + 2 * MU) * (VTY / 2) / 2; i += 256) {  // 18*8=144? (32 f2 = 16 f4) -> 18*16=288
        // recompute cleanly below
        break;
    }
    for (int i = tid; i < (VTX + 2 * MU) * (VTY / 4) * 2; i += 256) {  // 18 * 16 = 288 float4
        int r = i >> 4;
        int c = i & 15;
        int gx = x0 - MU + r;
        if (gx >= 0 && gx < SX)
            ((float4*)&sT[r][0])[c] = ((const float4*)(tsrc + base + (size_t)gx * SY + y0))[c];
    }
    // stage TV rows x0-5 .. x0+7 : 5 planes * 13 rows * 8 float4 = 520
    for (int i = tid; i < 5 * (VTX + MU) * (VTY / 4); i += 256) {
        int j   = i / ((VTX + MU) * (VTY / 4));      // /104
        int rem = i - j * ((VTX + MU) * (VTY / 4));
        int r   = rem >> 3;
        int c   = rem & 7;
        int gx  = x0 - MU + r;
        if (gx >= 0 && gx < SX)
            ((float4*)&sTV[j][r][0])[c] =
                ((const float4*)(TV + (size_t)j * NPIX + base + (size_t)gx * SY + y0))[c];
    }
    __syncthreads();

    int xi = x0 + tx;
    int yi = y0 + ty;
    size_t idx = base + (size_t)xi * SY + yi;

    float2 ct = sT[tx + MU][ty];

    float sx = 0.0f, sy = 0.0f;
#pragma unroll
    for (int k = -MU; k <= MU; ++k) {
        int nx = xi + k;
        if (nx < 0 || nx >= SX) continue;
        float2 nt = sT[tx + MU + k][ty];
        float th;
        if (k > 0)      th =  sTV[k - 1][tx + MU][ty];
        else if (k < 0) th = -sTV[-k - 1][tx + MU + k][ty];
        else            th =  0.0f;
        float dot = (ct.x * nt.x) + (ct.y * nt.y);
        float w   = ((th + 1.0f) * dot) * 0.5f;
        sx = sx + (nt.x * w);
        sy = sy + (nt.y * w);
    }
    float n = sqrtf((sx * sx) + (sy * sy));
    float d = (n == 0.0f) ? 1.0f : n;
    tdst[idx] = make_float2(sx / d, sy / d);
}

// Stage 3b: H-pass. One block per image row; stage the whole tsrc row (512 f2)
// and all 5 TH row-segments in LDS (14.3 KB). 2 px/thread at stride 256 so all
// LDS reads are lane-consecutive (conflict-free). Bit-exact vs reference.
__global__ __launch_bounds__(256) void k_etf_h(const float2* __restrict__ tsrc,
                                               float2* __restrict__ tdst,
                                               const float* __restrict__ TH) {
#pragma clang fp contract(off)
    int tid = threadIdx.x;
    int xi  = blockIdx.y;
    int b   = blockIdx.z;
    size_t rowbase = (size_t)b * SX * SY + (size_t)xi * SY;

    __shared__ __align__(16) float2 sT[SY];        // 4 KB
    __shared__ __align__(16) float  sTH[5][SY];    // 10 KB

    // stage tsrc row: 256 float4
    ((float4*)sT)[tid] = ((const float4*)(tsrc + rowbase))[tid];
    // stage 5 TH rows: 5 * 128 float4
    for (int i = tid; i < 5 * (SY / 4); i += 256) {
        int j = i >> 7;
        int c = i & 127;
        ((float4*)&sTH[0][0])[i] = ((const float4*)(TH + (size_t)j * NPIX + rowbase))[c];
    }
    __syncthreads();

#pragma unroll
    for (int half = 0; half < 2; ++half) {
        int yi = tid + half * 256;
        float2 ct = sT[yi];
        float sx = 0.0f, sy = 0.0f;
#pragma unroll
        for (int k = -MU; k <= MU; ++k) {
            int ny = yi + k;
            if (ny < 0 || ny >= SY) continue;
            float2 nt = sT[ny];
            float th;
            if (k > 0)      th =  sTH[k - 1][yi];
            else if (k < 0) th = -sTH[-k - 1][ny];
            else            th =  0.0f;
            float dot = (ct.x * nt.x) + (ct.y * nt.y);
            float w   = ((th + 1.0f) * dot) * 0.5f;
            sx = sx + (nt.x * w);
            sy = sy + (nt.y * w);
        }
        float n = sqrtf((sx * sx) + (sy * sy));
        float d = (n == 0.0f) ? 1.0f : n;
        tdst[rowbase + yi] = make_float2(sx / d, sy / d);
    }
}

// Stage 3 (fallback, inline ocml tanh) — only if workspace is too small.
__global__ void k_etf(const float2* __restrict__ tsrc, float2* __restrict__ tdst,
                      const float* __restrict__ mag, int vert) {
#pragma clang fp contract(off)
    int yi = blockIdx.x * blockDim.x + threadIdx.x;
    int xi = blockIdx.y;
    int b  = blockIdx.z;
    size_t base = (size_t)b * SX * SY;
    size_t idx  = base + (size_t)xi * SY + yi;

    float  cm = mag[idx];
    float2 ct = tsrc[idx];

    float sx = 0.0f, sy = 0.0f;
    for (int k = -MU; k <= MU; ++k) {
        int nx = xi + (vert ? k : 0);
        int ny = yi + (vert ? 0 : k);
        if (nx < 0 || nx >= SX || ny < 0 || ny >= SY) continue;
        size_t nidx = base + (size_t)nx * SY + ny;
        float  nm = mag[nidx];
        float2 nt = tsrc[nidx];
        float dot = (ct.x * nt.x) + (ct.y * nt.y);
        float th  = (float)tanh((double)(nm - cm));
        float w   = ((th + 1.0f) * dot) * 0.5f;
        sx = sx + (nt.x * w);
        sy = sy + (nt.y * w);
    }
    float n = sqrtf((sx * sx) + (sy * sy));
    float d = (n == 0.0f) ? 1.0f : n;
    tdst[idx] = make_float2(sx / d, sy / d);
}

// Stage 4: DoG along the perpendicular of the ETF
__global__ void k_dog(const float* __restrict__ img, const float2* __restrict__ etf,
                      float* __restrict__ dog, DogW w) {
#pragma clang fp contract(off)
    int yi = blockIdx.x * blockDim.x + threadIdx.x;
    int xi = blockIdx.y;
    int b  = blockIdx.z;
    size_t base = (size_t)b * SX * SY;
    size_t idx  = base + (size_t)xi * SY + yi;

    float2 e = etf[idx];
    float perx = -e.y;
    float pery =  e.x;
    float xf = (float)xi, yf = (float)yi;

    float acc = 0.0f;
#pragma unroll
    for (int t = -3; t <= 3; ++t) {
        float tf  = (float)t;
        float ptx = xf + (perx * tf);
        float pty = yf + (pery * tf);
        int px = (int)rintf(fminf(fmaxf(ptx, 0.0f), (float)(SX - 1)));
        int py = (int)rintf(fminf(fmaxf(pty, 0.0f), (float)(SY - 1)));
        float il = img[base + (size_t)px * SY + py];
        acc = acc + (il * w.g[t + 3]);
    }
    dog[idx] = acc / w.tw;
}

// Stage 5: FDoG. The two trace directions are independent dependent-load
// chains; walk them interleaved (2x ILP), fold in exact reference order.
__global__ void k_fdog(const float* __restrict__ dog, const float2* __restrict__ etf,
                       int* __restrict__ out, FdogW w) {
#pragma clang fp contract(off)
    int yi = blockIdx.x * blockDim.x + threadIdx.x;
    int xi = blockIdx.y;
    int b  = blockIdx.z;
    size_t base = (size_t)b * SX * SY;
    size_t idx  = base + (size_t)xi * SY + yi;

    float d1[9];
    float d2[10];
    float2 e0 = etf[idx];
    float2 e1 = e0, e2 = e0;
    int p1x = xi, p1y = yi;
    int p2x = xi, p2y = yi;
    d2[0] = dog[idx];

#pragma unroll
    for (int s = 1; s <= 9; ++s) {
        // chain 1: dir = -1
        float fx1 = (float)p1x + (e1.x * -1.0f);
        float fy1 = (float)p1y + (e1.y * -1.0f);
        p1x = (int)rintf(fminf(fmaxf(fx1, 0.0f), (float)(SX - 1)));
        p1y = (int)rintf(fminf(fmaxf(fy1, 0.0f), (float)(SY - 1)));
        size_t i1 = base + (size_t)p1x * SY + p1y;
        // chain 2: dir = +1
        float fx2 = (float)p2x + (e2.x * 1.0f);
        float fy2 = (float)p2y + (e2.y * 1.0f);
        p2x = (int)rintf(fminf(fmaxf(fx2, 0.0f), (float)(SX - 1)));
        p2y = (int)rintf(fminf(fmaxf(fy2, 0.0f), (float)(SY - 1)));
        size_t i2 = base + (size_t)p2x * SY + p2y;

        d1[s - 1] = dog[i1];
        d2[s]     = dog[i2];
        if (s < 9) {
            e1 = etf[i1];
            e2 = etf[i2];
        }
    }

    float acc = 0.0f;
#pragma unroll
    for (int s = 1; s <= 9; ++s) acc = acc + (d1[s - 1] * w.g[s]);
    acc = acc + (d2[0] * w.g[0]);
#pragma unroll
    for (int s = 1; s <= 9; ++s) acc = acc + (d2[s] * w.g[s]);

    float fv = acc / w.tw;
    float th = 1.0f + fast_tanh_f32(fv);
    out[idx] = ((fv < 0.0f) && (th < 0.7f)) ? 0 : 1;
}

static double gpdf(double v, double sig) {
    return exp(-(v * v) / (2.0 * sig * sig)) / (sqrt(2.0 * M_PI) * sig);
}

extern "C" void kernel_launch(void* const* d_in, const int* in_sizes, int n_in,
                              void* d_out, int out_size, void* d_ws, size_t ws_size,
                              hipStream_t stream) {
    const float* img = (const float*)d_in[0];
    int* out = (int*)d_out;
    char* ws = (char*)d_ws;

    // Fast-path workspace layout (60 MB + 16 KB + 4 B):
    //   mag [0,4MB) | tA [4,12) | tB [12,20) (dog aliases) | TV [20,40) | TH [40,60)
    //   partial [60MB, +16KB) | maxbits [+4)
    const size_t need = (size_t)60 * MB + NBLOCKS * sizeof(float) + 4;
    bool fast = ws_size >= need;

    float*  mag = (float*)(ws);
    float2* tA  = (float2*)(ws + (size_t)4  * MB);
    float2* tB  = (float2*)(ws + (size_t)12 * MB);
    float*  dog = (float*)(ws + (size_t)12 * MB);
    float*  TV  = (float*)(ws + (size_t)20 * MB);
    float*  TH  = (float*)(ws + (size_t)40 * MB);
    size_t  tail = fast ? (size_t)60 * MB : (size_t)20 * MB;
    float*        partial = (float*)(ws + tail);
    unsigned int* maxbits = (unsigned int*)(ws + tail + NBLOCKS * sizeof(float));

    dim3 blk(256, 1, 1);
    dim3 grd(SY / 256, SX, BN);
    dim3 vgrd(SY / VTY, SX / VTX, BN);
    dim3 hgrd(1, SX, BN);

    k_sobel<<<grd, blk, 0, stream>>>(img, mag, tA, partial);
    k_reduce<<<1, 256, 0, stream>>>(partial, maxbits);

    float2* src = tA;
    float2* dst = tB;
    if (fast) {
        k_tanh<<<grd, blk, 0, stream>>>(mag, maxbits, TV, TH);
        for (int it = 0; it < 3; ++it) {
            k_etf_v<<<vgrd, blk, 0, stream>>>(src, dst, TV);
            { float2* t = src; src = dst; dst = t; }
            k_etf_h<<<hgrd, blk, 0, stream>>>(src, dst, TH);
            { float2* t = src; src = dst; dst = t; }
        }
    } else {
        k_norm<<<NPIX / 256, 256, 0, stream>>>(mag, maxbits);
        for (int it = 0; it < 3; ++it) {
            k_etf<<<grd, blk, 0, stream>>>(src, dst, mag, 1);
            { float2* t = src; src = dst; dst = t; }
            k_etf<<<grd, blk, 0, stream>>>(src, dst, mag, 0);
            { float2* t = src; src = dst; dst = t; }
        }
    }
    float* dogbuf = (src == tA) ? dog : (float*)tA;

    DogW dw;
    {
        double tw = 0.0;
        for (int t = -3; t <= 3; ++t) {
            double g = gpdf((double)t, 1.0) - 0.99 * gpdf((double)t, 1.6);
            dw.g[t + 3] = (float)g;
            tw += g;
        }
        dw.tw = (float)tw;
    }
    k_dog<<<grd, blk, 0, stream>>>(img, src, dogbuf, dw);

    FdogW fw;
    {
        for (int s = 0; s <= 9; ++s) fw.g[s] = (float)gpdf((double)s, 3.0);
        double tw = 0.0;
        for (int s = 1; s <= 9; ++s) tw += gpdf((double)s, 3.0);
        for (int s = 0; s <= 9; ++s) tw += gpdf((double)s, 3.0);
        fw.tw = (float)tw;
    }
    k_fdog<<<grd, blk, 0, stream>>>(dogbuf, src, out, fw);
}